// Round 13
// baseline (58.408 us; speedup 1.0000x reference)
//
#include <hip/hip_runtime.h>
#include <stdint.h>

#define HW   4096      // 64*64 spatial per batch
#define NEMB 1024

typedef float        f32x4  __attribute__((ext_vector_type(4)));
typedef short        h16x8  __attribute__((ext_vector_type(8)));
typedef unsigned int u32x4  __attribute__((ext_vector_type(4)));

// pack 2 fp32 -> 2 fp16 (RTZ) in one u32 (lo = first operand)
#define CVTPKH(D, LO, HI) asm("v_cvt_pkrtz_f16_f32 %0, %1, %2" : "=v"(D) : "v"(LO), "v"(HI))

// ---------------- init: counts/errsum zero, ens1, f16 codebook, keys poison -------
__global__ __launch_bounds__(128) void vq_init(const float* __restrict__ emb,
                                               unsigned int* __restrict__ counts,
                                               float* __restrict__ errsum,
                                               float* __restrict__ ens1,
                                               unsigned int* __restrict__ embh,
                                               unsigned int* __restrict__ keys) {
    const int gid  = blockIdx.x * 128 + threadIdx.x;   // 0..2047
    const int k    = gid >> 1;
    const int half = gid & 1;
    if (half == 0) counts[k] = 0u;
    if (gid == 0) *errsum = 0.0f;
    // poison keys: 32 u32 per thread
    {
        u32x4 ff = {~0u, ~0u, ~0u, ~0u};
        #pragma unroll
        for (int i = 0; i < 8; ++i)
            *(u32x4*)&keys[gid * 32 + i * 4] = ff;
    }
    const float* e = emb + k * 64 + half * 32;
    unsigned int* dst = embh + k * 32 + half * 16;
    float nrm = 0.0f;
    #pragma unroll
    for (int c = 0; c < 4; ++c) {
        f32x4 v0 = *(const f32x4*)(e + c * 8);
        f32x4 v1 = *(const f32x4*)(e + c * 8 + 4);
        nrm += v0.x*v0.x + v0.y*v0.y + v0.z*v0.z + v0.w*v0.w
             + v1.x*v1.x + v1.y*v1.y + v1.z*v1.z + v1.w*v1.w;
        u32x4 w;
        CVTPKH(w.x, v0.x, v0.y); CVTPKH(w.y, v0.z, v0.w);
        CVTPKH(w.z, v1.x, v1.y); CVTPKH(w.w, v1.z, v1.w);
        *(u32x4*)&dst[c * 4] = w;
    }
    float o = __shfl_xor(nrm, 1, 64);
    if (half == 0) ens1[k] = 1.0f + (nrm + o);   // order arbitrary: screen-only
}

// ---------------- screen: 2048 x 256. block = 128 samples x 256 embs --------------
// tile = bid>>2 (samples), q = bid&3 (emb quarter). Wave wv owns 64 embs
// (8 B-frags = 32 VGPR); per-sample min -> LDS combine -> global atomicMin.
__global__ __launch_bounds__(256, 4)
void vq_screen(const float* __restrict__ z, const float* __restrict__ ens1,
               const unsigned int* __restrict__ embh,
               unsigned int* __restrict__ keys)
{
    __shared__ __attribute__((aligned(16))) unsigned int zh[128 * 36]; // f16 pairs, padded rows
    __shared__ __attribute__((aligned(16))) unsigned int kd[4][128];

    const int t    = threadIdx.x;
    const int bid  = blockIdx.x;
    const int tile = bid >> 2;
    const int q    = bid & 3;
    const int n0   = tile * 128;
    const int bb   = n0 >> 12;
    const int hw0  = n0 & 4095;
    const float* zb = z + bb * (64 * HW) + hw0;

    const int l   = t & 63;
    const int wv  = t >> 6;     // 0..3
    const int col = l & 15;
    const int bg  = l >> 4;     // 0..3

    // ---- persistent B-frags: 64 embs/wave (rows q*256 + wv*64 + cg*16 + col) ----
    u32x4 b0[4], b1[4];
    float en[4];
    {
        const int row0 = q * 256 + wv * 64 + col;
        #pragma unroll
        for (int cg = 0; cg < 4; ++cg) {
            const unsigned int* eb = embh + (row0 + cg * 16) * 32 + bg * 4;
            b0[cg] = *(const u32x4*)eb;
            b1[cg] = *(const u32x4*)(eb + 16);
            en[cg] = ens1[row0 + cg * 16];
        }
    }
    #pragma unroll
    for (int cg = 0; cg < 4; ++cg)
        asm volatile("" : "+v"(b0[cg]), "+v"(b1[cg]), "+v"(en[cg]));

    // ---- zh from global: thread = (x = t&127, half = t>>7), 4 chunks each ----
    {
        const int x  = t & 127;
        const int hf = t >> 7;
        #pragma unroll
        for (int ci = 0; ci < 4; ++ci) {
            const int c = hf * 4 + ci;          // chunk 0..7 (d = 8c..8c+7)
            u32x4 w;
            CVTPKH(w.x, zb[(8*c + 0) * HW + x], zb[(8*c + 1) * HW + x]);
            CVTPKH(w.y, zb[(8*c + 2) * HW + x], zb[(8*c + 3) * HW + x]);
            CVTPKH(w.z, zb[(8*c + 4) * HW + x], zb[(8*c + 5) * HW + x]);
            CVTPKH(w.w, zb[(8*c + 6) * HW + x], zb[(8*c + 7) * HW + x]);
            *(u32x4*)&zh[x * 36 + ((c ^ (x & 7)) << 2)] = w;
        }
    }
    __syncthreads();

    // ---- 8 sample-tiles ----
    #pragma unroll 1
    for (int st = 0; st < 8; ++st) {
        const int xs = st * 16 + col;
        const int sA = bg ^ (xs & 7);
        u32x4 wa = *(const u32x4*)&zh[xs * 36 + sA * 4];
        u32x4 wb = *(const u32x4*)&zh[xs * 36 + (sA ^ 4) * 4];
        h16x8 a0 = __builtin_bit_cast(h16x8, wa);
        h16x8 a1 = __builtin_bit_cast(h16x8, wb);

        unsigned int k0 = ~0u, k1 = ~0u, k2 = ~0u, k3 = ~0u;
        #pragma unroll
        for (int cg = 0; cg < 4; ++cg) {
            f32x4 cc = {0.0f, 0.0f, 0.0f, 0.0f};
            cc = __builtin_amdgcn_mfma_f32_16x16x32_f16(a0, __builtin_bit_cast(h16x8, b0[cg]), cc, 0, 0, 0);
            cc = __builtin_amdgcn_mfma_f32_16x16x32_f16(a1, __builtin_bit_cast(h16x8, b1[cg]), cc, 0, 0, 0);
            const unsigned int kk = (unsigned int)(q * 256 + wv * 64 + cg * 16 + col);
            float s0 = fmaf(-2.0f, cc[0], en[cg]);
            float s1 = fmaf(-2.0f, cc[1], en[cg]);
            float s2 = fmaf(-2.0f, cc[2], en[cg]);
            float s3 = fmaf(-2.0f, cc[3], en[cg]);
            unsigned int q0 = (__builtin_bit_cast(unsigned int, s0) & ~1023u) | kk;
            unsigned int q1 = (__builtin_bit_cast(unsigned int, s1) & ~1023u) | kk;
            unsigned int q2 = (__builtin_bit_cast(unsigned int, s2) & ~1023u) | kk;
            unsigned int q3 = (__builtin_bit_cast(unsigned int, s3) & ~1023u) | kk;
            k0 = k0 < q0 ? k0 : q0;  k1 = k1 < q1 ? k1 : q1;
            k2 = k2 < q2 ? k2 : q2;  k3 = k3 < q3 ? k3 : q3;
        }
        #pragma unroll
        for (int mk = 1; mk <= 8; mk <<= 1) {
            unsigned int o0 = (unsigned int)__shfl_xor((int)k0, mk, 64);
            unsigned int o1 = (unsigned int)__shfl_xor((int)k1, mk, 64);
            unsigned int o2 = (unsigned int)__shfl_xor((int)k2, mk, 64);
            unsigned int o3 = (unsigned int)__shfl_xor((int)k3, mk, 64);
            k0 = k0 < o0 ? k0 : o0;  k1 = k1 < o1 ? k1 : o1;
            k2 = k2 < o2 ? k2 : o2;  k3 = k3 < o3 ? k3 : o3;
        }
        if (col == 0) {
            u32x4 kv = {k0, k1, k2, k3};          // C rows 4*bg + j
            *(u32x4*)&kd[wv][st * 16 + bg * 4] = kv;
        }
    }
    __syncthreads();

    // ---- combine 4 waves, one atomicMin per sample ----
    if (t < 128) {
        unsigned int ka = kd[0][t] < kd[1][t] ? kd[0][t] : kd[1][t];
        unsigned int kb = kd[2][t] < kd[3][t] ? kd[2][t] : kd[3][t];
        atomicMin(&keys[n0 + t], ka < kb ? ka : kb);
    }
}

// ---------------- out: gather + STE write + histogram + error --------------------
// grid 512 x 256. block = 128 samples; thread (x = t&127, cg = t>>7: 32 channels).
__global__ __launch_bounds__(256)
void vq_out(const float* __restrict__ z, const float* __restrict__ emb,
            const unsigned int* __restrict__ keys,
            float* __restrict__ out, unsigned int* __restrict__ counts,
            float* __restrict__ errsum)
{
    __shared__ float errw[4];
    const int t   = threadIdx.x;
    const int n0  = blockIdx.x * 128;
    const int bb  = n0 >> 12;
    const int hw0 = n0 & 4095;
    const int x   = t & 127;
    const int cg  = t >> 7;

    const int idx = (int)(keys[n0 + x] & 1023u);
    if (t < 128) atomicAdd(&counts[idx], 1u);

    const float* er = emb + idx * 64;
    const float* zp = z + bb * (64 * HW) + hw0 + x;
    float* ob = out + bb * (64 * HW) + hw0 + x;
    float part = 0.0f;
    #pragma unroll
    for (int cq = 0; cq < 8; ++cq) {
        const int c = cg * 32 + cq * 4;
        f32x4 e4 = *(const f32x4*)&er[c];
        float z0 = zp[(c+0) * HW];
        float z1 = zp[(c+1) * HW];
        float z2 = zp[(c+2) * HW];
        float z3 = zp[(c+3) * HW];
        ob[(c+0) * HW] = z0 + (e4.x - z0);
        ob[(c+1) * HW] = z1 + (e4.y - z1);
        ob[(c+2) * HW] = z2 + (e4.z - z2);
        ob[(c+3) * HW] = z3 + (e4.w - z3);
        float d0 = z0 - e4.x, d1 = z1 - e4.y, d2 = z2 - e4.z, d3 = z3 - e4.w;
        part = fmaf(d0, d0, part); part = fmaf(d1, d1, part);
        part = fmaf(d2, d2, part); part = fmaf(d3, d3, part);
    }
    {
        float s = part;
        #pragma unroll
        for (int off = 32; off >= 1; off >>= 1) s += __shfl_down(s, off, 64);
        if ((t & 63) == 0) errw[t >> 6] = s;
    }
    __syncthreads();
    if (t == 0) atomicAdd(errsum, (errw[0] + errw[1]) + (errw[2] + errw[3]));
}

// ---------------- finalize: scalars ----------------
__global__ __launch_bounds__(256) void vq_fin(const unsigned int* __restrict__ counts,
                                              const float* __restrict__ errsum,
                                              float* __restrict__ scal)
{
    __shared__ float part[4];
    const int t = threadIdx.x;
    float s = 0.0f;
    for (int k = t; k < NEMB; k += 256) {
        float p = (float)counts[k] * (1.0f / 65536.0f);
        s += p * logf(p + 1e-10f);
    }
    #pragma unroll
    for (int off = 32; off >= 1; off >>= 1) s += __shfl_down(s, off, 64);
    if ((t & 63) == 0) part[t >> 6] = s;
    __syncthreads();
    if (t == 0) {
        float tot = (part[0] + part[1]) + (part[2] + part[3]);
        float es  = *errsum;
        scal[0] = 1.25f * (es * (1.0f / 4194304.0f));  // loss = 1.25 * mse
        scal[1] = expf(-tot);                          // perplexity
        scal[2] = es * (1.0f / 65536.0f);              // avg_error
    }
}

extern "C" void kernel_launch(void* const* d_in, const int* in_sizes, int n_in,
                              void* d_out, int out_size, void* d_ws, size_t ws_size,
                              hipStream_t stream) {
    const float* z   = (const float*)d_in[0];
    const float* emb = (const float*)d_in[1];
    float* out = (float*)d_out;
    unsigned int* counts = (unsigned int*)d_ws;
    float* errsum = (float*)((char*)d_ws + 4096);
    float* ens1   = (float*)((char*)d_ws + 8192);
    unsigned int* embh = (unsigned int*)((char*)d_ws + 16384);    // 128 KB
    unsigned int* keys = (unsigned int*)((char*)d_ws + 147456);   // 256 KB

    vq_init<<<16, 128, 0, stream>>>(emb, counts, errsum, ens1, embh, keys);
    vq_screen<<<2048, 256, 0, stream>>>(z, ens1, embh, keys);
    vq_out<<<512, 256, 0, stream>>>(z, emb, keys, out, counts, errsum);
    vq_fin<<<1, 256, 0, stream>>>(counts, errsum, out + 4194304);
}

// Round 14
// 44.553 us; speedup vs baseline: 1.3110x; 1.3110x over previous
//
#include <hip/hip_runtime.h>
#include <stdint.h>

#define HW   4096      // 64*64 spatial per batch
#define NEMB 1024

typedef float        f32x4  __attribute__((ext_vector_type(4)));
typedef short        bf16x8 __attribute__((ext_vector_type(8)));
typedef unsigned int u32x4  __attribute__((ext_vector_type(4)));

// pack 2 fp32 -> 2 bf16 in one u32 (lo = first operand)
#define CVTPK(D, LO, HI) asm("v_cvt_pk_bf16_f32 %0, %1, %2" : "=v"(D) : "v"(LO), "v"(HI))

// direct global->LDS DMA, 16B per lane
__device__ __forceinline__ void gload_lds16(const float* g, float* l) {
    __builtin_amdgcn_global_load_lds(
        (const __attribute__((address_space(1))) void*)(uintptr_t)g,
        (__attribute__((address_space(3))) void*)(uintptr_t)l, 16, 0, 0);
}

// ---------------- init: zero counts + errsum, ens[k] = 1 + ||e_k||^2 --------------
// 16 x 128, half-row per thread (ens order-insensitive: screen-only, epilogue exact).
__global__ __launch_bounds__(128) void vq_init(const float* __restrict__ emb,
                                               unsigned int* __restrict__ counts,
                                               float* __restrict__ errsum,
                                               float* __restrict__ ens) {
    const int gid  = blockIdx.x * 128 + threadIdx.x;   // 0..2047
    const int k    = gid >> 1;
    const int half = gid & 1;
    if (half == 0) counts[k] = 0u;
    if (gid == 0) *errsum = 0.0f;
    const float* e = emb + k * 64 + half * 32;
    float nrm = 0.0f;
    #pragma unroll
    for (int c = 0; c < 4; ++c) {
        f32x4 v0 = *(const f32x4*)(e + c * 8);
        f32x4 v1 = *(const f32x4*)(e + c * 8 + 4);
        nrm += v0.x*v0.x + v0.y*v0.y + v0.z*v0.z + v0.w*v0.w
             + v1.x*v1.x + v1.y*v1.y + v1.z*v1.z + v1.w*v1.w;
    }
    float o = __shfl_xor(nrm, 1, 64);
    if (half == 0) ens[k] = 1.0f + (nrm + o);
}

// ---------------- main: MFMA distance screen + fused argmin + exact epilogue ------
// grid 512 x 512 (2 blocks/CU, 16 waves/CU). Block: 128 samples.
// Wave: 16 samples x all 1024 embs (4 k-tiles of 256 staged bf16 in LDS).
__global__ __launch_bounds__(512, 4)
void vq_main(const float* __restrict__ z, const float* __restrict__ emb,
             const float* __restrict__ ens,
             float* __restrict__ out, unsigned int* __restrict__ counts,
             float* __restrict__ errsum)
{
    __shared__ __attribute__((aligned(16))) float z_lds[64 * 128];   // fp32 [d][x]
    __shared__ __attribute__((aligned(16))) unsigned int et_w[256 * 32]; // bf16 tile, row r: slot s = chunk s^(r&7)
    __shared__ __attribute__((aligned(16))) float ens_lds[NEMB];
    __shared__ int   idx_sh[128];
    __shared__ float errp[512];

    const int t   = threadIdx.x;
    const int n0  = blockIdx.x * 128;
    const int bb  = n0 >> 12;
    const int hw0 = n0 & 4095;
    const float* zb = z + bb * (64 * HW) + hw0;

    // ---- DMA z tile fp32 [d][128] ----
    #pragma unroll
    for (int it = 0; it < 4; ++it) {
        const int p = it * 512 + t;            // 16B chunk 0..2047
        gload_lds16(zb + (p >> 5) * HW + (p & 31) * 4, z_lds + p * 4);
    }
    // ---- DMA ens ----
    if (t < 256) gload_lds16(ens + t * 4, ens_lds + t * 4);

    // ---- stage et tile 0: fp32 load -> bf16 cvt -> swizzled ds_write ----
    #pragma unroll
    for (int it = 0; it < 4; ++it) {
        const int q = it * 512 + t;            // bf16 16B chunk 0..2047
        const int r = q >> 3, c = q & 7;
        const float* s2 = emb + r * 64 + c * 8;
        f32x4 e0 = *(const f32x4*)s2;
        f32x4 e1 = *(const f32x4*)(s2 + 4);
        u32x4 v;
        CVTPK(v.x, e0.x, e0.y); CVTPK(v.y, e0.z, e0.w);
        CVTPK(v.z, e1.x, e1.y); CVTPK(v.w, e1.z, e1.w);
        *(u32x4*)&et_w[r * 32 + ((c ^ (r & 7)) << 2)] = v;
    }
    __syncthreads();   // z_lds + ens_lds + et tile0 visible

    const int l   = t & 63;     // lane
    const int wv  = t >> 6;     // wave 0..7 -> samples wv*16..wv*16+15
    const int col = l & 15;     // A-row selector (input) / C col = emb (output)
    const int bg  = l >> 4;     // k-group

    // ---- A fragments: z bf16, row=col, k = 8*bg + e (same rule as B) ----
    bf16x8 a0, a1;
    {
        const int xs = wv * 16 + col;
        u32x4 wa, wb;
        #pragma unroll
        for (int p2 = 0; p2 < 4; ++p2) {
            float lo = z_lds[(bg * 8 + p2 * 2    ) * 128 + xs];
            float hi = z_lds[(bg * 8 + p2 * 2 + 1) * 128 + xs];
            CVTPK(wa[p2], lo, hi);
            float lo2 = z_lds[(32 + bg * 8 + p2 * 2    ) * 128 + xs];
            float hi2 = z_lds[(32 + bg * 8 + p2 * 2 + 1) * 128 + xs];
            CVTPK(wb[p2], lo2, hi2);
        }
        a0 = __builtin_bit_cast(bf16x8, wa);
        a1 = __builtin_bit_cast(bf16x8, wb);
    }

    const int slot0 = bg ^ (col & 7);
    const unsigned int* ep0 = et_w + col * 32 + slot0 * 4;
    const unsigned int* ep1 = et_w + col * 32 + (slot0 ^ 4) * 4;
    const float* ensp = ens_lds + col;

    unsigned int mkey[4] = {~0u, ~0u, ~0u, ~0u};

    #pragma unroll
    for (int kt = 0; kt < 4; ++kt) {
        // T14: prefetch next tile's fp32 into regs (consumed after barrier)
        f32x4 pf[8];
        if (kt < 3) {
            const float* src = emb + (kt + 1) * 256 * 64;
            #pragma unroll
            for (int it = 0; it < 4; ++it) {
                const int q = it * 512 + t;
                const float* s2 = src + (q >> 3) * 64 + (q & 7) * 8;
                pf[it * 2]     = *(const f32x4*)s2;
                pf[it * 2 + 1] = *(const f32x4*)(s2 + 4);
            }
        }

        __builtin_amdgcn_s_setprio(1);
        #pragma unroll
        for (int i = 0; i < 16; ++i) {
            u32x4 bw0 = *(const u32x4*)(ep0 + i * 512);
            u32x4 bw1 = *(const u32x4*)(ep1 + i * 512);
            float en1 = ensp[kt * 256 + i * 16];
            f32x4 cc = {0.0f, 0.0f, 0.0f, 0.0f};
            cc = __builtin_amdgcn_mfma_f32_16x16x32_bf16(a0, __builtin_bit_cast(bf16x8, bw0), cc, 0, 0, 0);
            cc = __builtin_amdgcn_mfma_f32_16x16x32_bf16(a1, __builtin_bit_cast(bf16x8, bw1), cc, 0, 0, 0);
            const unsigned int kg = (unsigned int)(kt * 256 + i * 16 + col);
            #pragma unroll
            for (int j = 0; j < 4; ++j) {
                float s = fmaf(-2.0f, cc[j], en1);          // 1 + ||e||^2 - 2 z.e
                unsigned int key = (__builtin_bit_cast(unsigned int, s) & 0xFFFFFC00u) | kg;
                mkey[j] = mkey[j] < key ? mkey[j] : key;    // strict-first + idx tie-break
            }
        }
        __builtin_amdgcn_s_setprio(0);

        // early-cvt: pf -> bf16 words BEFORE the barrier (overlaps other waves' MFMA)
        u32x4 vv[4];
        if (kt < 3) {
            #pragma unroll
            for (int it = 0; it < 4; ++it) {
                CVTPK(vv[it].x, pf[it*2].x,   pf[it*2].y);
                CVTPK(vv[it].y, pf[it*2].z,   pf[it*2].w);
                CVTPK(vv[it].z, pf[it*2+1].x, pf[it*2+1].y);
                CVTPK(vv[it].w, pf[it*2+1].z, pf[it*2+1].w);
            }
        }

        __syncthreads();   // all waves done reading et[kt]
        if (kt < 3) {
            #pragma unroll
            for (int it = 0; it < 4; ++it) {
                const int q = it * 512 + t;
                const int r = q >> 3, c = q & 7;
                *(u32x4*)&et_w[r * 32 + ((c ^ (r & 7)) << 2)] = vv[it];
            }
            __syncthreads();   // et[kt+1] ready
        }
    }

    // ---- reduce argmin across the 16 cols (lanes sharing bg) ----
    #pragma unroll
    for (int j = 0; j < 4; ++j) {
        #pragma unroll
        for (int m = 1; m <= 8; m <<= 1) {
            unsigned int o = (unsigned int)__shfl_xor((int)mkey[j], m, 64);
            mkey[j] = mkey[j] < o ? mkey[j] : o;
        }
    }
    if (col == 0) {
        #pragma unroll
        for (int j = 0; j < 4; ++j)
            idx_sh[wv * 16 + bg * 4 + j] = (int)(mkey[j] & 1023u);  // C row = 4*bg + j
    }
    __syncthreads();

    // ---- histogram ----
    if (t < 128) atomicAdd(&counts[idx_sh[t]], 1u);

    // ---- epilogue: out = z + (e - z), exact fp32 error for chosen code ----
    {
        const int x  = t & 127;
        const int cg = t >> 7;     // 0..3 -> channels cg*16..+15
        const int idx = idx_sh[x];
        const float* er = emb + idx * 64;
        float* ob = out + bb * (64 * HW) + hw0 + x;
        float part = 0.0f;
        #pragma unroll
        for (int cq = 0; cq < 4; ++cq) {
            const int c = cg * 16 + cq * 4;
            f32x4 e4 = *(const f32x4*)&er[c];
            float z0 = z_lds[(c+0) * 128 + x];
            float z1 = z_lds[(c+1) * 128 + x];
            float z2 = z_lds[(c+2) * 128 + x];
            float z3 = z_lds[(c+3) * 128 + x];
            ob[(c+0) * HW] = z0 + (e4.x - z0);
            ob[(c+1) * HW] = z1 + (e4.y - z1);
            ob[(c+2) * HW] = z2 + (e4.z - z2);
            ob[(c+3) * HW] = z3 + (e4.w - z3);
            float d0 = z0 - e4.x, d1 = z1 - e4.y, d2 = z2 - e4.z, d3 = z3 - e4.w;
            part = fmaf(d0, d0, part); part = fmaf(d1, d1, part);
            part = fmaf(d2, d2, part); part = fmaf(d3, d3, part);
        }
        errp[t] = part;
    }
    __syncthreads();
    if (t < 128) {
        float s = (errp[t] + errp[t + 128]) + (errp[t + 256] + errp[t + 384]);
        #pragma unroll
        for (int off = 32; off >= 1; off >>= 1) s += __shfl_down(s, off, 64);
        if ((t & 63) == 0) atomicAdd(errsum, s);
    }
}

// ---------------- finalize: scalars ----------------
__global__ __launch_bounds__(256) void vq_fin(const unsigned int* __restrict__ counts,
                                              const float* __restrict__ errsum,
                                              float* __restrict__ scal)
{
    __shared__ float part[4];
    const int t = threadIdx.x;
    float s = 0.0f;
    for (int k = t; k < NEMB; k += 256) {
        float p = (float)counts[k] * (1.0f / 65536.0f);
        s += p * logf(p + 1e-10f);
    }
    #pragma unroll
    for (int off = 32; off >= 1; off >>= 1) s += __shfl_down(s, off, 64);
    if ((t & 63) == 0) part[t >> 6] = s;
    __syncthreads();
    if (t == 0) {
        float tot = (part[0] + part[1]) + (part[2] + part[3]);
        float es  = *errsum;
        scal[0] = 1.25f * (es * (1.0f / 4194304.0f));  // loss = 1.25 * mse
        scal[1] = expf(-tot);                          // perplexity
        scal[2] = es * (1.0f / 65536.0f);              // avg_error
    }
}

extern "C" void kernel_launch(void* const* d_in, const int* in_sizes, int n_in,
                              void* d_out, int out_size, void* d_ws, size_t ws_size,
                              hipStream_t stream) {
    const float* z   = (const float*)d_in[0];
    const float* emb = (const float*)d_in[1];
    float* out = (float*)d_out;
    unsigned int* counts = (unsigned int*)d_ws;
    float* errsum = (float*)((char*)d_ws + 4096);
    float* ens    = (float*)((char*)d_ws + 8192);

    vq_init<<<16, 128, 0, stream>>>(emb, counts, errsum, ens);
    vq_main<<<512, 512, 0, stream>>>(z, emb, ens, out, counts, errsum);
    vq_fin<<<1, 256, 0, stream>>>(counts, errsum, out + 4194304);
}